// Round 4
// baseline (264.868 us; speedup 1.0000x reference)
//
#include <hip/hip_runtime.h>
#include <hip/hip_bf16.h>

// Problem constants
#define TT   512
#define DD   64
#define NWK  4
#define STP  16
#define NPJ  15          // others per w
#define NBLK 60          // NWK * NPJ
#define CMAT (TT * TT)   // floats per cost matrix
// u-domain scale: u = R / (gamma * ln2), gamma = 5
#define CSCALE 0.2885390081777927f
#define USCALE 3.4657359027997265f   // gamma * ln2
#define BIGC   2.885390081777927e8f  // 1e9 * CSCALE

#define SA 132   // LDS leading stride (128 + 4 pad)

// ---------------------------------------------------------------------------
// Kernel 1: cost matrices, scaled by CSCALE. 128x128 tile per block, 256 thr,
// split 4+4 register tile per thread. grid (4,4,n).
// __launch_bounds__(256,1): do NOT let the allocator squeeze acc[8][8] into a
// high-occupancy VGPR budget (round-3 evidence: spill-bound inner loop).
// ---------------------------------------------------------------------------
__global__ __launch_bounds__(256, 1) void cost_kernel(const float* __restrict__ data,
                                                      const int* __restrict__ lens,
                                                      float* __restrict__ cost, int base) {
  int blk = base + blockIdx.z;
  int w = blk / NPJ, j = blk - w * NPJ;
  int la = lens[w * STP];
  int lb = lens[w * STP + 1 + j];
  int ti = blockIdx.y, tj = blockIdx.x;
  if (ti * 128 >= la || tj * 128 >= lb) return;

  __shared__ float As[DD][SA];   // k-major: As[k][r], r in [0,128)
  __shared__ float Bs[DD][SA];
  __shared__ float a2[128], b2[128];

  const float* A = data + ((size_t)(w * STP) * TT + (size_t)ti * 128) * DD;
  const float* B = data + ((size_t)(w * STP + 1 + j) * TT + (size_t)tj * 128) * DD;
  int t = threadIdx.x;

  #pragma unroll
  for (int i = 0; i < 8; ++i) {
    int idx = t + i * 256;        // [0, 2048)
    int r = idx & 127;            // row within tile
    int kq = idx >> 7;            // float4 index along k, [0,16)
    float4 va = *(const float4*)(A + r * DD + kq * 4);
    As[kq * 4 + 0][r] = va.x; As[kq * 4 + 1][r] = va.y;
    As[kq * 4 + 2][r] = va.z; As[kq * 4 + 3][r] = va.w;
    float4 vb = *(const float4*)(B + r * DD + kq * 4);
    Bs[kq * 4 + 0][r] = vb.x; Bs[kq * 4 + 1][r] = vb.y;
    Bs[kq * 4 + 2][r] = vb.z; Bs[kq * 4 + 3][r] = vb.w;
  }
  __syncthreads();
  if (t < 128) {
    float s = 0.f;
    for (int k = 0; k < DD; ++k) { float x = As[k][t]; s += x * x; }
    a2[t] = s;
  } else {
    float s = 0.f;
    for (int k = 0; k < DD; ++k) { float x = Bs[k][t - 128]; s += x * x; }
    b2[t - 128] = s;
  }
  __syncthreads();

  int r0 = (t >> 4) << 2;   // {0,4,...,60}
  int c0 = (t & 15) << 2;   // {0,4,...,60}
  float acc[8][8];
  #pragma unroll
  for (int i = 0; i < 8; ++i)
    #pragma unroll
    for (int q = 0; q < 8; ++q) acc[i][q] = 0.f;

  #pragma unroll 2
  for (int k = 0; k < DD; ++k) {
    float4 aL = *(const float4*)&As[k][r0];
    float4 aH = *(const float4*)&As[k][r0 + 64];
    float4 bL = *(const float4*)&Bs[k][c0];
    float4 bH = *(const float4*)&Bs[k][c0 + 64];
    acc[0][0] += aL.x * bL.x; acc[0][1] += aL.x * bL.y; acc[0][2] += aL.x * bL.z; acc[0][3] += aL.x * bL.w;
    acc[0][4] += aL.x * bH.x; acc[0][5] += aL.x * bH.y; acc[0][6] += aL.x * bH.z; acc[0][7] += aL.x * bH.w;
    acc[1][0] += aL.y * bL.x; acc[1][1] += aL.y * bL.y; acc[1][2] += aL.y * bL.z; acc[1][3] += aL.y * bL.w;
    acc[1][4] += aL.y * bH.x; acc[1][5] += aL.y * bH.y; acc[1][6] += aL.y * bH.z; acc[1][7] += aL.y * bH.w;
    acc[2][0] += aL.z * bL.x; acc[2][1] += aL.z * bL.y; acc[2][2] += aL.z * bL.z; acc[2][3] += aL.z * bL.w;
    acc[2][4] += aL.z * bH.x; acc[2][5] += aL.z * bH.y; acc[2][6] += aL.z * bH.z; acc[2][7] += aL.z * bH.w;
    acc[3][0] += aL.w * bL.x; acc[3][1] += aL.w * bL.y; acc[3][2] += aL.w * bL.z; acc[3][3] += aL.w * bL.w;
    acc[3][4] += aL.w * bH.x; acc[3][5] += aL.w * bH.y; acc[3][6] += aL.w * bH.z; acc[3][7] += aL.w * bH.w;
    acc[4][0] += aH.x * bL.x; acc[4][1] += aH.x * bL.y; acc[4][2] += aH.x * bL.z; acc[4][3] += aH.x * bL.w;
    acc[4][4] += aH.x * bH.x; acc[4][5] += aH.x * bH.y; acc[4][6] += aH.x * bH.z; acc[4][7] += aH.x * bH.w;
    acc[5][0] += aH.y * bL.x; acc[5][1] += aH.y * bL.y; acc[5][2] += aH.y * bL.z; acc[5][3] += aH.y * bL.w;
    acc[5][4] += aH.y * bH.x; acc[5][5] += aH.y * bH.y; acc[5][6] += aH.y * bH.z; acc[5][7] += aH.y * bH.w;
    acc[6][0] += aH.z * bL.x; acc[6][1] += aH.z * bL.y; acc[6][2] += aH.z * bL.z; acc[6][3] += aH.z * bL.w;
    acc[6][4] += aH.z * bH.x; acc[6][5] += aH.z * bH.y; acc[6][6] += aH.z * bH.z; acc[6][7] += aH.z * bH.w;
    acc[7][0] += aH.w * bL.x; acc[7][1] += aH.w * bL.y; acc[7][2] += aH.w * bL.z; acc[7][3] += aH.w * bL.w;
    acc[7][4] += aH.w * bH.x; acc[7][5] += aH.w * bH.y; acc[7][6] += aH.w * bH.z; acc[7][7] += aH.w * bH.w;
  }

  float* Cbase = cost + (size_t)blockIdx.z * CMAT;
  #pragma unroll
  for (int i = 0; i < 8; ++i) {
    int rr = (i < 4) ? (r0 + i) : (r0 + 60 + i);   // r0+64+(i-4)
    float ar = a2[rr];
    float* Crow = Cbase + (size_t)(ti * 128 + rr) * TT + tj * 128;
    float4 o;
    o.x = (ar + b2[c0 + 0] - 2.f * acc[i][0]) * CSCALE;
    o.y = (ar + b2[c0 + 1] - 2.f * acc[i][1]) * CSCALE;
    o.z = (ar + b2[c0 + 2] - 2.f * acc[i][2]) * CSCALE;
    o.w = (ar + b2[c0 + 3] - 2.f * acc[i][3]) * CSCALE;
    *(float4*)(Crow + c0) = o;
    float4 o2;
    o2.x = (ar + b2[c0 + 64] - 2.f * acc[i][4]) * CSCALE;
    o2.y = (ar + b2[c0 + 65] - 2.f * acc[i][5]) * CSCALE;
    o2.z = (ar + b2[c0 + 66] - 2.f * acc[i][6]) * CSCALE;
    o2.w = (ar + b2[c0 + 67] - 2.f * acc[i][7]) * CSCALE;
    *(float4*)(Crow + c0 + 64) = o2;
  }
}

// ---------------------------------------------------------------------------
// Soft-DTW DP cell in u-units: u = dc + min - log2(1 + 2^(min-med) + 2^(min-max))
// ---------------------------------------------------------------------------
__device__ __forceinline__ float dpcell(float dc, float a, float b, float c) {
  float mn = fminf(fminf(a, b), c);
  float mx = fmaxf(fmaxf(a, b), c);
  float md = __builtin_amdgcn_fmed3f(a, b, c);
  float e = 1.0f + __builtin_amdgcn_exp2f(mn - md) + __builtin_amdgcn_exp2f(mn - mx);
  return dc + mn - __builtin_amdgcn_logf(e);
}

// one DP step: consume CREG, refill it for group gg+2 (16 steps ahead)
#define DPSTEP(CREG, k, gg)                                                   \
  {                                                                           \
    int r = 8 * (gg) + (k) - ln;                                              \
    float dx = CREG.x, dy = CREG.y;                                           \
    {                                                                         \
      int rr = 8 * (gg) + 16 + (k) - ln;                                      \
      rr = rr < 0 ? 0 : (rr > 511 ? 511 : rr);                                \
      CREG = *(const float2*)(Cp + (size_t)rr * TT);                          \
    }                                                                         \
    if ((unsigned)r < 512u) {                                                 \
      float v0 = dpcell(dx, NLd, U0, NL);                                     \
      float v1 = dpcell(dy, U0, U1, v0);                                      \
      if (isT & (r == rt)) res = par ? v1 : v0;                               \
      NLd = NL; U0 = v0; U1 = v1; v1s = v1;                                   \
      if (wr63) {                                                             \
        bufB[q][r] = v1;                                                      \
        if (((r & 7) == 7) | (r == la - 1)) {                                 \
          __threadfence_block();                                              \
          *(volatile int*)&flags[q] = (r == la - 1) ? 512 : (r + 1);          \
        }                                                                     \
      }                                                                       \
    }                                                                         \
    float nb = __shfl_up(v1s, 1);                                             \
    if (ln == 0) nb = (q == 0) ? BIGC : bb[(k)];                              \
    NL = nb;                                                                  \
  }

#define DPGROUP(R0, R1, R2, R3, R4, R5, R6, R7, gg)                           \
  {                                                                           \
    if (q > 0) {                                                              \
      int need = 8 * (gg) + 9; if (need > la) need = la;                      \
      while (*(volatile int*)&flags[q - 1] < need) __builtin_amdgcn_s_sleep(1); \
      __threadfence_block();                                                  \
      _Pragma("unroll")                                                       \
      for (int kk = 0; kk < 8; ++kk) bb[kk] = bufB[q - 1][8 * (gg) + 1 + kk]; \
      if (((gg) == 0) & (ln == 0)) NL = bufB[q - 1][0];                       \
    }                                                                         \
    DPSTEP(R0, 0, gg) DPSTEP(R1, 1, gg) DPSTEP(R2, 2, gg) DPSTEP(R3, 3, gg)   \
    DPSTEP(R4, 4, gg) DPSTEP(R5, 5, gg) DPSTEP(R6, 6, gg) DPSTEP(R7, 7, gg)   \
  }

// ---------------------------------------------------------------------------
// Kernel 2: fused DP (blocks [0,ndp)) + gram (blocks [ndp, ndp+121)).
// DP: barrier-free systolic pipeline. 4 waves; wave q owns cols [128q,128q+128);
// lane owns 2 cols, lane-skew 1 row/lane (intra-wave boundary via shfl_up);
// wave->wave boundary via write-once LDS column + spin flags (8-row groups).
// Cost values live in a 16-reg named ring (2-group software pipeline).
// ---------------------------------------------------------------------------
__global__ __launch_bounds__(256, 1) void dp_gram_kernel(const float* __restrict__ cost,
                                                         const int* __restrict__ lens,
                                                         const float* __restrict__ data,
                                                         float* __restrict__ sdt,
                                                         float* __restrict__ gram,
                                                         int base, int ndp) {
  int bid = blockIdx.x;

  if (bid >= ndp) {
    // ---------------- gram path: 44x44 Gram over K = 32768 ----------------
    __shared__ float red[4][16];
    int g = bid - ndp;
    int bx = g / 11, by = g - bx * 11;
    int t = threadIdx.x;
    const float* Ar[4]; const float* Br[4];
    #pragma unroll
    for (int a = 0; a < 4; ++a) {
      int gx = bx * 4 + a;
      Ar[a] = data + (size_t)((gx / 11) * STP + gx % 11) * (TT * DD);
      int gy = by * 4 + a;
      Br[a] = data + (size_t)((gy / 11) * STP + gy % 11) * (TT * DD);
    }
    float acc[4][4];
    #pragma unroll
    for (int a = 0; a < 4; ++a)
      #pragma unroll
      for (int b = 0; b < 4; ++b) acc[a][b] = 0.f;
    for (int k = t * 4; k < TT * DD; k += 1024) {
      float4 av[4], bv[4];
      #pragma unroll
      for (int a = 0; a < 4; ++a) av[a] = *(const float4*)(Ar[a] + k);
      #pragma unroll
      for (int b = 0; b < 4; ++b) bv[b] = *(const float4*)(Br[b] + k);
      #pragma unroll
      for (int a = 0; a < 4; ++a)
        #pragma unroll
        for (int b = 0; b < 4; ++b)
          acc[a][b] += av[a].x * bv[b].x + av[a].y * bv[b].y +
                       av[a].z * bv[b].z + av[a].w * bv[b].w;
    }
    int wave = t >> 6, lane = t & 63;
    #pragma unroll
    for (int a = 0; a < 4; ++a)
      #pragma unroll
      for (int b = 0; b < 4; ++b) {
        float v = acc[a][b];
        for (int off = 32; off > 0; off >>= 1) v += __shfl_down(v, off);
        if (lane == 0) red[wave][a * 4 + b] = v;
      }
    __syncthreads();
    if (t < 16) {
      float v = red[0][t] + red[1][t] + red[2][t] + red[3][t];
      int a = t >> 2, b = t & 3;
      gram[(size_t)(bx * 4 + a) * 44 + by * 4 + b] = v;
    }
    return;
  }

  // -------------------------- DP path --------------------------
  __shared__ float bufB[3][512];   // boundary column per wave (write-once)
  __shared__ int flags[4];

  if (threadIdx.x < 4) flags[threadIdx.x] = 0;
  __syncthreads();

  int blk = base + bid;
  int w = blk / NPJ, j = blk - w * NPJ;
  int la = lens[w * STP];
  int lb = lens[w * STP + 1 + j];
  const float* C = cost + (size_t)bid * CMAT;

  int q = threadIdx.x >> 6, ln = threadIdx.x & 63;
  int c0 = q * 128 + ln * 2;
  const float* Cp = C + c0;
  bool wr63 = (q < 3) & (ln == 63);

  // target cell (la-1, lb-1)
  int qt = (lb - 1) >> 7;
  int lt = ((lb - 1) >> 1) & 63;
  int par = (lb - 1) & 1;
  int rt = la - 1;
  bool isT = (q == qt) && (ln == lt);

  float U0 = BIGC, U1 = BIGC;          // own cols, previous row
  float NL = BIGC;                     // left neighbor value, current row
  float NLd = (q == 0 && ln == 0) ? 0.0f : BIGC;  // left-diag (prev row)
  float v1s = BIGC;                    // last computed right-col value
  float res = 0.0f;
  float bb[8];

  int ngrp = (la + 70) >> 3;
  int ngrp2 = (ngrp + 1) & ~1;

  // prologue: fill the 16-reg ring with groups 0 and 1
  float2 a0, a1, a2r, a3, a4, a5, a6, a7;
  float2 b0, b1, b2r, b3, b4, b5, b6, b7;
  {
    #define PRELD(RG, kk, gg)                                    \
      { int rr = 8 * (gg) + (kk) - ln;                           \
        rr = rr < 0 ? 0 : (rr > 511 ? 511 : rr);                 \
        RG = *(const float2*)(Cp + (size_t)rr * TT); }
    PRELD(a0, 0, 0) PRELD(a1, 1, 0) PRELD(a2r, 2, 0) PRELD(a3, 3, 0)
    PRELD(a4, 4, 0) PRELD(a5, 5, 0) PRELD(a6, 6, 0) PRELD(a7, 7, 0)
    PRELD(b0, 0, 1) PRELD(b1, 1, 1) PRELD(b2r, 2, 1) PRELD(b3, 3, 1)
    PRELD(b4, 4, 1) PRELD(b5, 5, 1) PRELD(b6, 6, 1) PRELD(b7, 7, 1)
    #undef PRELD
  }

  for (int g = 0; g < ngrp2; g += 2) {
    DPGROUP(a0, a1, a2r, a3, a4, a5, a6, a7, g)
    DPGROUP(b0, b1, b2r, b3, b4, b5, b6, b7, (g + 1))
  }
  if (wr63) {
    __threadfence_block();
    *(volatile int*)&flags[q] = 512;   // release any remaining pollers
  }
  if (isT) sdt[blk] = res * USCALE;
}

// ---------------------------------------------------------------------------
// Kernel 4: final combine. block 640 = 10 waves; waves 0..8: one MMD pair each;
// wave 9: triplet losses; thread 0 writes the scalar.
// ---------------------------------------------------------------------------
__global__ __launch_bounds__(640) void final_kernel(const float* __restrict__ sdt,
                                                    const int* __restrict__ lens,
                                                    const float* __restrict__ gram,
                                                    float* __restrict__ out) {
  __shared__ float partial[16];
  int t = threadIdx.x, wave = t >> 6, lane = t & 63;
  if (wave < 9) {
    const int piA[9] = {0, 0, 0, 1, 1, 2, 2, 3, 3};
    const int pjA[9] = {1, 2, 3, 2, 3, 1, 3, 1, 2};
    int P = piA[wave], Q = pjA[wave];
    float s1 = 0.f;
    for (int c = lane; c < 484; c += 64) {
      int i = c / 22, jj = c - (c / 22) * 22;
      int gi = (i < 11) ? P * 11 + i : Q * 11 + (i - 11);
      int gj = (jj < 11) ? P * 11 + jj : Q * 11 + (jj - 11);
      s1 += gram[gi * 44 + gi] + gram[gj * 44 + gj] - 2.f * gram[gi * 44 + gj];
    }
    for (int off = 32; off > 0; off >>= 1) s1 += __shfl_down(s1, off);
    s1 = __shfl(s1, 0);
    float bw = s1 / 462.0f * 0.25f;     // /(ns^2-ns) then / KMUL^(KNUM//2)=4
    float inv[5];
    float b = bw;
    #pragma unroll
    for (int qq = 0; qq < 5; ++qq) { inv[qq] = -1.0f / b; b *= 2.0f; }
    float s2 = 0.f;
    for (int c = lane; c < 484; c += 64) {
      int i = c / 22, jj = c - (c / 22) * 22;
      int gi = (i < 11) ? P * 11 + i : Q * 11 + (i - 11);
      int gj = (jj < 11) ? P * 11 + jj : Q * 11 + (jj - 11);
      float l2 = gram[gi * 44 + gi] + gram[gj * 44 + gj] - 2.f * gram[gi * 44 + gj];
      float kk = 0.f;
      #pragma unroll
      for (int qq = 0; qq < 5; ++qq) kk += __expf(l2 * inv[qq]);
      float sgn = ((i < 11) == (jj < 11)) ? 1.0f : -1.0f;
      s2 += sgn * kk;
    }
    for (int off = 32; off > 0; off >>= 1) s2 += __shfl_down(s2, off);
    if (lane == 0) partial[wave] = s2 / 121.0f;
  } else {
    float term = 0.f;
    if (wave == 9 && lane < 4) {
      int w = lane;
      float L0 = (float)lens[w * STP];
      float dist[15];
      for (int qq = 0; qq < 15; ++qq)
        dist[qq] = sdt[w * NPJ + qq] / (L0 + (float)lens[w * STP + 1 + qq]);
      float ca = 0.f, cb = 0.f;
      for (int a = 0; a < 6; ++a) ca += dist[a];
      ca *= (1.0f / 6.0f);
      for (int bq = 6; bq < 11; ++bq) cb += dist[bq];
      cb *= (1.0f / 5.0f);
      float lksum = 0.f; int nz = 0;
      for (int a = 0; a < 6; ++a)
        for (int bq = 6; bq < 15; ++bq) {
          float x = dist[a] + 1.0f - dist[bq];   // MARGIN = 1.0
          if (x > 0.f) { lksum += x; nz += 1; }
        }
      float intra = 0.f;
      for (int a = 0; a < 6; ++a) intra += dist[a] - ca;
      float inter = fmaxf(0.f, 1.0f - fabsf(ca - cb));  // BETA = 1.0
      term = lksum / (float)(nz + 1) + intra * 0.1f + inter * 0.1f;  // P=R=0.1
    }
    if (wave == 9) {
      term += __shfl_down(term, 1);
      term += __shfl_down(term, 2);
      if (lane == 0) partial[9] = term * 0.25f;   // mean over NW=4
    }
  }
  __syncthreads();
  if (t == 0) {
    float mx = 0.0f;                               // zero-pad in the max
    for (int p = 0; p < 9; ++p) mx = fmaxf(mx, partial[p]);
    out[0] = partial[9] + 0.01f * mx;              // ALPHA = 0.01
  }
}

// ---------------------------------------------------------------------------
extern "C" void kernel_launch(void* const* d_in, const int* in_sizes, int n_in,
                              void* d_out, int out_size, void* d_ws, size_t ws_size,
                              hipStream_t stream) {
  const float* data = (const float*)d_in[0];
  const int* lens = (const int*)d_in[1];
  float* out = (float*)d_out;

  float* sdtb  = (float*)d_ws;                      // 60 floats
  float* gramb = sdtb + 64;                         // 44*44 floats
  float* costb = (float*)((char*)d_ws + 8192);      // cost chunks

  size_t avail = (ws_size > 8192) ? (ws_size - 8192) : 0;
  int chunk = (int)(avail / ((size_t)CMAT * sizeof(float)));
  if (chunk < 1) chunk = 1;
  if (chunk > NBLK) chunk = NBLK;

  bool first = true;
  for (int base = 0; base < NBLK; base += chunk) {
    int n = NBLK - base;
    if (n > chunk) n = chunk;
    cost_kernel<<<dim3(4, 4, n), 256, 0, stream>>>(data, lens, costb, base);
    int extra = first ? 121 : 0;   // fuse gram onto otherwise-idle CUs
    dp_gram_kernel<<<n + extra, 256, 0, stream>>>(costb, lens, data, sdtb, gramb, base, n);
    first = false;
  }
  final_kernel<<<1, 640, 0, stream>>>(sdtb, lens, gramb, out);
}

// Round 5
// 242.008 us; speedup vs baseline: 1.0945x; 1.0945x over previous
//
#include <hip/hip_runtime.h>
#include <hip/hip_bf16.h>

// Problem constants
#define TT   512
#define DD   64
#define NWK  4
#define STP  16
#define NPJ  15          // others per w
#define NBLK 60          // NWK * NPJ
#define CMAT (TT * TT)   // floats per cost matrix
// u-domain scale: u = R / (gamma * ln2), gamma = 5
#define CSCALE 0.2885390081777927f
#define USCALE 3.4657359027997265f   // gamma * ln2
#define BIGC   2.885390081777927e8f  // 1e9 * CSCALE

// XOR swizzle for k-major LDS (stride 128): bank = (r ^ ((k>>2 &7)<<2)) % 32
#define SWZ(k) (((((k) >> 2) & 7)) << 2)

// ---------------------------------------------------------------------------
// Kernel 1: cost matrices, scaled by CSCALE. 128x128 tile per block, 256 thr,
// 8x8 register tile. Coalesced staging + XOR-swizzled k-major LDS (all LDS
// access <=2-way bank aliased = free). 1-deep pipelined k-loop. grid (4,4,n).
// ---------------------------------------------------------------------------
__global__ __launch_bounds__(256, 1) void cost_kernel(const float* __restrict__ data,
                                                      const int* __restrict__ lens,
                                                      float* __restrict__ cost, int base) {
  int blk = base + blockIdx.z;
  int w = blk / NPJ, j = blk - w * NPJ;
  int la = lens[w * STP];
  int lb = lens[w * STP + 1 + j];
  int ti = blockIdx.y, tj = blockIdx.x;
  if (ti * 128 >= la || tj * 128 >= lb) return;

  __shared__ float As[DD][128];   // swizzled k-major
  __shared__ float Bs[DD][128];
  __shared__ float a2[128], b2[128];

  const float* A = data + ((size_t)(w * STP) * TT + (size_t)ti * 128) * DD;
  const float* B = data + ((size_t)(w * STP + 1 + j) * TT + (size_t)tj * 128) * DD;
  int t = threadIdx.x;

  #pragma unroll
  for (int i = 0; i < 8; ++i) {
    int f = t + i * 256;          // float4 id in [0,2048): fully coalesced
    int r = f >> 4;               // row
    int k0 = (f & 15) << 2;       // k offset {0,4,...,60}
    int cs = r ^ SWZ(k0);         // swizzled col (same for k0..k0+3)
    float4 va = *(const float4*)(A + r * DD + k0);
    As[k0 + 0][cs] = va.x; As[k0 + 1][cs] = va.y;
    As[k0 + 2][cs] = va.z; As[k0 + 3][cs] = va.w;
    float4 vb = *(const float4*)(B + r * DD + k0);
    Bs[k0 + 0][cs] = vb.x; Bs[k0 + 1][cs] = vb.y;
    Bs[k0 + 2][cs] = vb.z; Bs[k0 + 3][cs] = vb.w;
  }
  __syncthreads();
  if (t < 128) {
    float s = 0.f;
    #pragma unroll 8
    for (int k = 0; k < DD; ++k) { float x = As[k][t ^ SWZ(k)]; s += x * x; }
    a2[t] = s;
  } else {
    int u = t - 128;
    float s = 0.f;
    #pragma unroll 8
    for (int k = 0; k < DD; ++k) { float x = Bs[k][u ^ SWZ(k)]; s += x * x; }
    b2[u] = s;
  }
  __syncthreads();

  int r0 = (t >> 4) << 2;   // {0,4,...,60}
  int c0 = (t & 15) << 2;   // {0,4,...,60}
  float acc[8][8];
  #pragma unroll
  for (int i = 0; i < 8; ++i)
    #pragma unroll
    for (int q = 0; q < 8; ++q) acc[i][q] = 0.f;

  float4 aL = *(const float4*)&As[0][r0];
  float4 aH = *(const float4*)&As[0][r0 + 64];
  float4 bL = *(const float4*)&Bs[0][c0];
  float4 bH = *(const float4*)&Bs[0][c0 + 64];

  #pragma unroll 4
  for (int k = 0; k < DD; ++k) {
    int kn = (k + 1) & 63;            // wrap: k=63 reloads k=0 (unused)
    int sw = SWZ(kn);
    float4 naL = *(const float4*)&As[kn][r0 ^ sw];
    float4 naH = *(const float4*)&As[kn][(r0 + 64) ^ sw];
    float4 nbL = *(const float4*)&Bs[kn][c0 ^ sw];
    float4 nbH = *(const float4*)&Bs[kn][(c0 + 64) ^ sw];
    float a[8] = {aL.x, aL.y, aL.z, aL.w, aH.x, aH.y, aH.z, aH.w};
    float b[8] = {bL.x, bL.y, bL.z, bL.w, bH.x, bH.y, bH.z, bH.w};
    #pragma unroll
    for (int i = 0; i < 8; ++i)
      #pragma unroll
      for (int q = 0; q < 8; ++q)
        acc[i][q] += a[i] * b[q];
    aL = naL; aH = naH; bL = nbL; bH = nbH;
  }

  float* Cbase = cost + (size_t)blockIdx.z * CMAT;
  #pragma unroll
  for (int i = 0; i < 8; ++i) {
    int rr = (i < 4) ? (r0 + i) : (r0 + 60 + i);   // r0+64+(i-4)
    float ar = a2[rr];
    float* Crow = Cbase + (size_t)(ti * 128 + rr) * TT + tj * 128;
    float4 o;
    o.x = (ar + b2[c0 + 0] - 2.f * acc[i][0]) * CSCALE;
    o.y = (ar + b2[c0 + 1] - 2.f * acc[i][1]) * CSCALE;
    o.z = (ar + b2[c0 + 2] - 2.f * acc[i][2]) * CSCALE;
    o.w = (ar + b2[c0 + 3] - 2.f * acc[i][3]) * CSCALE;
    *(float4*)(Crow + c0) = o;
    float4 o2;
    o2.x = (ar + b2[c0 + 64] - 2.f * acc[i][4]) * CSCALE;
    o2.y = (ar + b2[c0 + 65] - 2.f * acc[i][5]) * CSCALE;
    o2.z = (ar + b2[c0 + 66] - 2.f * acc[i][6]) * CSCALE;
    o2.w = (ar + b2[c0 + 67] - 2.f * acc[i][7]) * CSCALE;
    *(float4*)(Crow + c0 + 64) = o2;
  }
}

// ---------------------------------------------------------------------------
// Soft-DTW DP cell in u-units: u = dc + min - log2(1 + 2^(min-med) + 2^(min-max))
// ---------------------------------------------------------------------------
__device__ __forceinline__ float dpcell(float dc, float a, float b, float c) {
  float mn = fminf(fminf(a, b), c);
  float mx = fmaxf(fmaxf(a, b), c);
  float md = __builtin_amdgcn_fmed3f(a, b, c);
  float e = 1.0f + __builtin_amdgcn_exp2f(mn - md) + __builtin_amdgcn_exp2f(mn - mx);
  return dc + mn - __builtin_amdgcn_logf(e);
}

// prefetch next group's cost pair (row clamped; unused rows inert)
#define LDNXT(kk, gg)                                                         \
  { int rr = 8 * ((gg) + 1) + (kk) - ln;                                      \
    rr = rr < 0 ? 0 : (rr > 511 ? 511 : rr);                                  \
    nxt[kk] = *(const float2*)(Cp + (size_t)rr * TT); }

// one DP row-step: consume cur[kk]
#define DPSTEP(kk, gg)                                                        \
  {                                                                           \
    int r = 8 * (gg) + (kk) - ln;                                             \
    if ((unsigned)r < 512u) {                                                 \
      float v0 = dpcell(cur[kk].x, NLd, U0, NL);                              \
      float v1 = dpcell(cur[kk].y, U0, U1, v0);                               \
      if (isT & (r == rt)) res = par ? v1 : v0;                               \
      NLd = NL; U0 = v0; U1 = v1; v1s = v1;                                   \
      if (wr63) {                                                             \
        bufB[q][r] = v1;                                                      \
        if ((r & 7) == 7) {                                                   \
          asm volatile("s_waitcnt lgkmcnt(0)" ::: "memory");  /* LDS-only release */ \
          *(volatile int*)&flags[q] = r + 1;                                  \
        }                                                                     \
      }                                                                       \
    }                                                                         \
    float nb = __shfl_up(v1s, 1);                                             \
    if (ln == 0) nb = (q == 0) ? BIGC : bb[kk];                               \
    NL = nb;                                                                  \
  }

#define DPGROUP(gg)                                                           \
  {                                                                           \
    LDNXT(0, gg) LDNXT(1, gg) LDNXT(2, gg) LDNXT(3, gg)                       \
    LDNXT(4, gg) LDNXT(5, gg) LDNXT(6, gg) LDNXT(7, gg)                       \
    __builtin_amdgcn_sched_barrier(0);   /* pin loads above the poll */       \
    if (q > 0) {                                                              \
      int need = 8 * (gg) + 9; if (need > la) need = la;                      \
      while (*(volatile int*)&flags[q - 1] < need) __builtin_amdgcn_s_sleep(1); \
      asm volatile("" ::: "memory");     /* compiler acquire; no vmcnt drain */ \
      bb[0] = bufB[q - 1][8 * (gg) + 1]; bb[1] = bufB[q - 1][8 * (gg) + 2];   \
      bb[2] = bufB[q - 1][8 * (gg) + 3]; bb[3] = bufB[q - 1][8 * (gg) + 4];   \
      bb[4] = bufB[q - 1][8 * (gg) + 5]; bb[5] = bufB[q - 1][8 * (gg) + 6];   \
      bb[6] = bufB[q - 1][8 * (gg) + 7]; bb[7] = bufB[q - 1][8 * (gg) + 8];   \
    }                                                                         \
    DPSTEP(0, gg) DPSTEP(1, gg) DPSTEP(2, gg) DPSTEP(3, gg)                   \
    DPSTEP(4, gg) DPSTEP(5, gg) DPSTEP(6, gg) DPSTEP(7, gg)                   \
    cur[0] = nxt[0]; cur[1] = nxt[1]; cur[2] = nxt[2]; cur[3] = nxt[3];       \
    cur[4] = nxt[4]; cur[5] = nxt[5]; cur[6] = nxt[6]; cur[7] = nxt[7];       \
  }

// ---------------------------------------------------------------------------
// Kernel 2: fused DP (blocks [0,ndp)) + gram (blocks [ndp, ndp+121)).
// DP: barrier-free systolic pipeline. 4 waves; wave q owns cols [128q,128q+128);
// lane owns 2 cols, lane-skew 1 row/lane (intra-wave boundary via shfl_up);
// wave->wave boundary via write-once LDS column + spin flags (8-row groups).
// All inter-wave sync is lgkm-only: the global cost prefetch never drains.
// ---------------------------------------------------------------------------
__global__ __launch_bounds__(256, 1) void dp_gram_kernel(const float* __restrict__ cost,
                                                         const int* __restrict__ lens,
                                                         const float* __restrict__ data,
                                                         float* __restrict__ sdt,
                                                         float* __restrict__ gram,
                                                         int base, int ndp) {
  int bid = blockIdx.x;

  if (bid >= ndp) {
    // ---------------- gram path: 44x44 Gram over K = 32768 ----------------
    __shared__ float red[4][16];
    int g = bid - ndp;
    int bx = g / 11, by = g - bx * 11;
    int t = threadIdx.x;
    const float* Ar[4]; const float* Br[4];
    #pragma unroll
    for (int a = 0; a < 4; ++a) {
      int gx = bx * 4 + a;
      Ar[a] = data + (size_t)((gx / 11) * STP + gx % 11) * (TT * DD);
      int gy = by * 4 + a;
      Br[a] = data + (size_t)((gy / 11) * STP + gy % 11) * (TT * DD);
    }
    float acc[4][4];
    #pragma unroll
    for (int a = 0; a < 4; ++a)
      #pragma unroll
      for (int b = 0; b < 4; ++b) acc[a][b] = 0.f;
    for (int k = t * 4; k < TT * DD; k += 1024) {
      float4 av[4], bv[4];
      #pragma unroll
      for (int a = 0; a < 4; ++a) av[a] = *(const float4*)(Ar[a] + k);
      #pragma unroll
      for (int b = 0; b < 4; ++b) bv[b] = *(const float4*)(Br[b] + k);
      #pragma unroll
      for (int a = 0; a < 4; ++a)
        #pragma unroll
        for (int b = 0; b < 4; ++b)
          acc[a][b] += av[a].x * bv[b].x + av[a].y * bv[b].y +
                       av[a].z * bv[b].z + av[a].w * bv[b].w;
    }
    int wave = t >> 6, lane = t & 63;
    #pragma unroll
    for (int a = 0; a < 4; ++a)
      #pragma unroll
      for (int b = 0; b < 4; ++b) {
        float v = acc[a][b];
        for (int off = 32; off > 0; off >>= 1) v += __shfl_down(v, off);
        if (lane == 0) red[wave][a * 4 + b] = v;
      }
    __syncthreads();
    if (t < 16) {
      float v = red[0][t] + red[1][t] + red[2][t] + red[3][t];
      int a = t >> 2, b = t & 3;
      gram[(size_t)(bx * 4 + a) * 44 + by * 4 + b] = v;
    }
    return;
  }

  // -------------------------- DP path --------------------------
  __shared__ float bufB[3][640];   // boundary column per wave (write-once)
  __shared__ int flags[4];

  if (threadIdx.x < 4) flags[threadIdx.x] = 0;
  __syncthreads();

  int blk = base + bid;
  int w = blk / NPJ, j = blk - w * NPJ;
  int la = lens[w * STP];
  int lb = lens[w * STP + 1 + j];
  const float* C = cost + (size_t)bid * CMAT;

  int q = threadIdx.x >> 6, ln = threadIdx.x & 63;
  int c0 = q * 128 + ln * 2;
  const float* Cp = C + c0;
  bool wr63 = (q < 3) & (ln == 63);

  // target cell (la-1, lb-1)
  int qt = (lb - 1) >> 7;
  int lt = ((lb - 1) >> 1) & 63;
  int par = (lb - 1) & 1;
  int rt = la - 1;
  bool isT = (q == qt) && (ln == lt);

  float U0 = BIGC, U1 = BIGC;          // own cols, previous row
  float NL = BIGC;                     // left neighbor value, current row
  float NLd = (q == 0 && ln == 0) ? 0.0f : BIGC;  // left-diag (prev row)
  float v1s = BIGC;                    // last computed right-col value
  float res = 0.0f;
  float bb[8];

  int ngrp = (la + 70) >> 3;

  float2 cur[8], nxt[8];
  #pragma unroll
  for (int k = 0; k < 8; ++k) {
    int rr = k - ln; rr = rr < 0 ? 0 : rr;
    cur[k] = *(const float2*)(Cp + (size_t)rr * TT);
  }

  for (int g = 0; g < ngrp; ++g) {
    DPGROUP(g)
  }
  if (wr63) {
    asm volatile("s_waitcnt lgkmcnt(0)" ::: "memory");
    *(volatile int*)&flags[q] = 512;   // release any remaining pollers
  }
  if (isT) sdt[blk] = res * USCALE;
}

// ---------------------------------------------------------------------------
// Kernel 4: final combine. block 640 = 10 waves; waves 0..8: one MMD pair each;
// wave 9: triplet losses; thread 0 writes the scalar.
// ---------------------------------------------------------------------------
__global__ __launch_bounds__(640) void final_kernel(const float* __restrict__ sdt,
                                                    const int* __restrict__ lens,
                                                    const float* __restrict__ gram,
                                                    float* __restrict__ out) {
  __shared__ float partial[16];
  int t = threadIdx.x, wave = t >> 6, lane = t & 63;
  if (wave < 9) {
    const int piA[9] = {0, 0, 0, 1, 1, 2, 2, 3, 3};
    const int pjA[9] = {1, 2, 3, 2, 3, 1, 3, 1, 2};
    int P = piA[wave], Q = pjA[wave];
    float s1 = 0.f;
    for (int c = lane; c < 484; c += 64) {
      int i = c / 22, jj = c - (c / 22) * 22;
      int gi = (i < 11) ? P * 11 + i : Q * 11 + (i - 11);
      int gj = (jj < 11) ? P * 11 + jj : Q * 11 + (jj - 11);
      s1 += gram[gi * 44 + gi] + gram[gj * 44 + gj] - 2.f * gram[gi * 44 + gj];
    }
    for (int off = 32; off > 0; off >>= 1) s1 += __shfl_down(s1, off);
    s1 = __shfl(s1, 0);
    float bw = s1 / 462.0f * 0.25f;     // /(ns^2-ns) then / KMUL^(KNUM//2)=4
    float inv[5];
    float b = bw;
    #pragma unroll
    for (int qq = 0; qq < 5; ++qq) { inv[qq] = -1.0f / b; b *= 2.0f; }
    float s2 = 0.f;
    for (int c = lane; c < 484; c += 64) {
      int i = c / 22, jj = c - (c / 22) * 22;
      int gi = (i < 11) ? P * 11 + i : Q * 11 + (i - 11);
      int gj = (jj < 11) ? P * 11 + jj : Q * 11 + (jj - 11);
      float l2 = gram[gi * 44 + gi] + gram[gj * 44 + gj] - 2.f * gram[gi * 44 + gj];
      float kk = 0.f;
      #pragma unroll
      for (int qq = 0; qq < 5; ++qq) kk += __expf(l2 * inv[qq]);
      float sgn = ((i < 11) == (jj < 11)) ? 1.0f : -1.0f;
      s2 += sgn * kk;
    }
    for (int off = 32; off > 0; off >>= 1) s2 += __shfl_down(s2, off);
    if (lane == 0) partial[wave] = s2 / 121.0f;
  } else {
    float term = 0.f;
    if (wave == 9 && lane < 4) {
      int w = lane;
      float L0 = (float)lens[w * STP];
      float dist[15];
      for (int qq = 0; qq < 15; ++qq)
        dist[qq] = sdt[w * NPJ + qq] / (L0 + (float)lens[w * STP + 1 + qq]);
      float ca = 0.f, cb = 0.f;
      for (int a = 0; a < 6; ++a) ca += dist[a];
      ca *= (1.0f / 6.0f);
      for (int bq = 6; bq < 11; ++bq) cb += dist[bq];
      cb *= (1.0f / 5.0f);
      float lksum = 0.f; int nz = 0;
      for (int a = 0; a < 6; ++a)
        for (int bq = 6; bq < 15; ++bq) {
          float x = dist[a] + 1.0f - dist[bq];   // MARGIN = 1.0
          if (x > 0.f) { lksum += x; nz += 1; }
        }
      float intra = 0.f;
      for (int a = 0; a < 6; ++a) intra += dist[a] - ca;
      float inter = fmaxf(0.f, 1.0f - fabsf(ca - cb));  // BETA = 1.0
      term = lksum / (float)(nz + 1) + intra * 0.1f + inter * 0.1f;  // P=R=0.1
    }
    if (wave == 9) {
      term += __shfl_down(term, 1);
      term += __shfl_down(term, 2);
      if (lane == 0) partial[9] = term * 0.25f;   // mean over NW=4
    }
  }
  __syncthreads();
  if (t == 0) {
    float mx = 0.0f;                               // zero-pad in the max
    for (int p = 0; p < 9; ++p) mx = fmaxf(mx, partial[p]);
    out[0] = partial[9] + 0.01f * mx;              // ALPHA = 0.01
  }
}

// ---------------------------------------------------------------------------
extern "C" void kernel_launch(void* const* d_in, const int* in_sizes, int n_in,
                              void* d_out, int out_size, void* d_ws, size_t ws_size,
                              hipStream_t stream) {
  const float* data = (const float*)d_in[0];
  const int* lens = (const int*)d_in[1];
  float* out = (float*)d_out;

  float* sdtb  = (float*)d_ws;                      // 60 floats
  float* gramb = sdtb + 64;                         // 44*44 floats
  float* costb = (float*)((char*)d_ws + 8192);      // cost chunks

  size_t avail = (ws_size > 8192) ? (ws_size - 8192) : 0;
  int chunk = (int)(avail / ((size_t)CMAT * sizeof(float)));
  if (chunk < 1) chunk = 1;
  if (chunk > NBLK) chunk = NBLK;

  bool first = true;
  for (int base = 0; base < NBLK; base += chunk) {
    int n = NBLK - base;
    if (n > chunk) n = chunk;
    cost_kernel<<<dim3(4, 4, n), 256, 0, stream>>>(data, lens, costb, base);
    int extra = first ? 121 : 0;   // fuse gram onto otherwise-idle CUs
    dp_gram_kernel<<<n + extra, 256, 0, stream>>>(costb, lens, data, sdtb, gramb, base, n);
    first = false;
  }
  final_kernel<<<1, 640, 0, stream>>>(sdtb, lens, gramb, out);
}